// Round 1
// baseline (1069.912 us; speedup 1.0000x reference)
//
#include <hip/hip_runtime.h>
#include <math.h>

#define NWAY 5
#define KSHOT 5
#define BB 4
#define QQ 75
#define CC 640
#define MM 196
#define BQ (BB*QQ)          // 300
#define MP 208              // packed A rows per bq
#define NCOL 1024           // padded flat col space (980 real)
#define NREAL 980

// ---- ws layout (float offsets) ----
#define BPK_OFF   0
#define BPK_SZF   (BB*NCOL*CC/2)            // 1,310,720 (fp16 region)
#define APK_OFF   (BPK_OFF + BPK_SZF)
#define APK_SZF   ((BQ*MP + 64)*CC/2)       // +64 pad rows so 256-row tile OOB stays in-region
#define GSTAT_OFF (APK_OFF + APK_SZF)       // even -> 8B aligned
#define GSTAT_N   (BQ*NWAY*MP)              // 312,000 u64
#define NRMS_OFF  (GSTAT_OFF + 2*GSTAT_N)
#define NRMS_SZ   (BB*NWAY*MM)              // 3,920
#define NRMQ_OFF  (NRMS_OFF + NRMS_SZ)
#define NRMQ_SZ   (BQ*MM)                   // 58,800

typedef __attribute__((ext_vector_type(8))) _Float16 half8;
typedef __attribute__((ext_vector_type(4))) float floatx4;

// ---------------- fused prep: A-pack (3000 blocks) + B mean-pack (200 blocks) ----------------
__global__ void k_prep(const float* __restrict__ sx, const float* __restrict__ qx,
                       _Float16* __restrict__ Apk, _Float16* __restrict__ Bpk,
                       float* __restrict__ nrmq, float* __restrict__ nrms) {
    __shared__ float T[64 * 197];         // 50,432 B
    int t = threadIdx.x;
    int blk = blockIdx.x;
    if (blk < 3000) {
        // ---- query pack: Apk[bq][m][c] fp16 (unnormalized) + nrmq partials ----
        int bq = blk / 10, cc = blk % 10;
        int c0 = cc * 64;
        const float* Q = qx + (size_t)bq * CC * MM + (size_t)c0 * MM;
        for (int idx = t; idx < 64 * MM; idx += 256) {
            int ci = idx / MM, m = idx - ci * MM;
            T[ci * 197 + m] = Q[idx];
        }
        __syncthreads();
        _Float16* out = Apk + (size_t)bq * MP * CC;
        int mloc = t >> 3, cj8 = t & 7;   // 32 rows x 8 col-groups per pass
        #pragma unroll
        for (int r = 0; r < 7; r++) {
            int mm = r * 32 + mloc;
            if (mm < MP) {
                half8 v;
                #pragma unroll
                for (int k = 0; k < 8; k++) {
                    float f = (mm < MM) ? T[(cj8 * 8 + k) * 197 + mm] : 0.f;
                    v[k] = (_Float16)f;
                }
                *(half8*)&out[(size_t)mm * CC + c0 + cj8 * 8] = v;
            }
        }
        if (t < MM) {
            float ss = 0.f;
            for (int ci = 0; ci < 64; ci++) { float v = T[ci * 197 + t]; ss += v * v; }
            atomicAdd(&nrmq[bq * MM + t], ss);
        }
    } else {
        // ---- support k-shot mean + pack: Bpk[b][col=n*196+ms][c] fp16 (unnormalized) + nrms ----
        int bb = blk - 3000;
        int bn = bb / 10, cc = bb % 10;
        int b = bn / NWAY, n = bn % NWAY;
        int c0 = cc * 64;
        const float* S = sx + (size_t)bn * KSHOT * CC * MM + (size_t)c0 * MM;
        for (int idx = t; idx < 64 * MM; idx += 256) {
            int ci = idx / MM, m = idx - ci * MM;
            float s = 0.f;
            #pragma unroll
            for (int k = 0; k < KSHOT; k++) s += S[(size_t)k * CC * MM + idx];
            T[ci * 197 + m] = s * 0.2f;
        }
        __syncthreads();
        _Float16* out = Bpk + ((size_t)b * NCOL + (size_t)n * MM) * CC;
        int mloc = t >> 3, cj8 = t & 7;
        #pragma unroll
        for (int r = 0; r < 7; r++) {
            int mm = r * 32 + mloc;
            if (mm < MM) {
                half8 v;
                #pragma unroll
                for (int k = 0; k < 8; k++)
                    v[k] = (_Float16)T[(cj8 * 8 + k) * 197 + mm];
                *(half8*)&out[(size_t)mm * CC + c0 + cj8 * 8] = v;
            }
        }
        if (t < MM) {
            float ss = 0.f;
            for (int ci = 0; ci < 64; ci++) { float v = T[ci * 197 + t]; ss += v * v; }
            atomicAdd(&nrms[bn * MM + t], ss);
        }
    }
}

// ---------------- MFMA similarity v2: 256x256 tile, 8 waves (2Mx4N), BK=64 ----------------
// LDS 128 KiB: 2 buffers x { A 256x64 halfs | B 256x64 halfs }, chunk-XOR swizzled rows.
// Pipeline: stage tile t+1 -> buf (t+1)&1 BEFORE computing tile t from buf t&1; one
// __syncthreads per K-tile (its vmcnt(0) drain lands a full compute-phase after issue).
// wm=1 waves skip mrep 5..7 (rows 208..255 are pad garbage): -18.75% MFMA.
__global__ __launch_bounds__(512, 2) void k_sim(
    const _Float16* __restrict__ Apk, const _Float16* __restrict__ Bpk,
    const float* __restrict__ nrms, unsigned long long* __restrict__ gstat)
{
    __shared__ __align__(16) _Float16 Lds[65536];   // 131,072 B

    int hw = blockIdx.x;
    int logical = (hw & 7) * 150 + (hw >> 3);   // XCD-bijective: 4 col-blocks of a bq per XCD
    int bq = logical >> 2, cblk = logical & 3;
    int b = bq / QQ;

    int t = threadIdx.x, w = t >> 6, lane = t & 63;
    int wm = w >> 2, wn = w & 3;
    int q = lane >> 4, l15 = lane & 15, s7 = l15 & 7;

    const _Float16* Ab = Apk + (size_t)bq * MP * CC;
    const _Float16* Bb = Bpk + ((size_t)b * NCOL + (size_t)cblk * 256) * CC;

    // staging source offsets (halfs): call a covers rows/cols a*64 .. +63, 8KB per call
    int voff[4];
    {
        int rr = t >> 3, slot = t & 7;
        #pragma unroll
        for (int a = 0; a < 4; a++) {
            int r = a * 64 + rr;
            voff[a] = r * CC + ((slot ^ (r & 7)) << 3);
        }
    }

    // fragment read bases (halfs, within one 32768-half buffer)
    int aoff[8], boff[4];
    #pragma unroll
    for (int m = 0; m < 8; m++) aoff[m] = (wm * 128 + m * 16 + l15) * 64;
    #pragma unroll
    for (int n = 0; n < 4; n++) boff[n] = 16384 + (wn * 64 + n * 16 + l15) * 64;

    floatx4 acc[8][4];
    #pragma unroll
    for (int m = 0; m < 8; m++)
        #pragma unroll
        for (int n = 0; n < 4; n++) acc[m][n] = (floatx4){0.f, 0.f, 0.f, 0.f};

    #define STAGE(TT)                                                                  \
        do {                                                                           \
            int nb_ = ((TT) & 1) << 15;                                                \
            int c0_ = (TT) * 64;                                                       \
            _Pragma("unroll")                                                          \
            for (int a = 0; a < 4; a++) {                                              \
                __builtin_amdgcn_global_load_lds(                                      \
                    (const __attribute__((address_space(1))) void*)(Ab + voff[a] + c0_),\
                    (__attribute__((address_space(3))) void*)(Lds + nb_ + a * 4096 + w * 512), \
                    16, 0, 0);                                                         \
                __builtin_amdgcn_global_load_lds(                                      \
                    (const __attribute__((address_space(1))) void*)(Bb + voff[a] + c0_),\
                    (__attribute__((address_space(3))) void*)(Lds + nb_ + 16384 + a * 4096 + w * 512), \
                    16, 0, 0);                                                         \
            }                                                                          \
        } while (0)

    // prologue: tile 0 -> buf 0
    STAGE(0);
    __syncthreads();

    for (int tt = 0; tt < 10; tt++) {
        int cb = (tt & 1) << 15;
        if (tt < 9) STAGE(tt + 1);          // issue next tile into the other buffer

        half8 bf[4][2];
        #pragma unroll
        for (int n = 0; n < 4; n++)
            #pragma unroll
            for (int ks = 0; ks < 2; ks++)
                bf[n][ks] = *(const half8*)&Lds[cb + boff[n] + (((ks * 4 + q) ^ s7) << 3)];

        __builtin_amdgcn_s_setprio(1);
        #define MFMA_BLOCK(MTOP)                                                       \
            _Pragma("unroll")                                                          \
            for (int m = 0; m < (MTOP); m++) {                                         \
                half8 af0 = *(const half8*)&Lds[cb + aoff[m] + ((q ^ s7) << 3)];       \
                half8 af1 = *(const half8*)&Lds[cb + aoff[m] + (((4 + q) ^ s7) << 3)]; \
                _Pragma("unroll")                                                      \
                for (int n = 0; n < 4; n++) {                                          \
                    acc[m][n] = __builtin_amdgcn_mfma_f32_16x16x32_f16(af0, bf[n][0], acc[m][n], 0, 0, 0); \
                    acc[m][n] = __builtin_amdgcn_mfma_f32_16x16x32_f16(af1, bf[n][1], acc[m][n], 0, 0, 0); \
                }                                                                      \
            }
        if (wm == 0) { MFMA_BLOCK(8) } else { MFMA_BLOCK(5) }   // wm=1 rows >=208 are pad
        __builtin_amdgcn_s_setprio(0);

        __syncthreads();   // vmcnt(0)+lgkmcnt(0)+barrier: drains the t+1 loads issued above
    }

    // ---- epilogue: fold 4 nrep cols into <=2 class keys, 16-lane butterfly, atomicMax ----
    int wbase = cblk * 256 + wn * 64;     // 64-col window, straddles <=1 class boundary
    int clsLo = wbase / 196;
    int clsHi = clsLo + 1;
    bool hasHi = (((wbase + 63) / 196) != clsLo) && (clsHi < NWAY);
    float invv[4]; int msv[4], isLo[4], valid[4];
    #pragma unroll
    for (int n = 0; n < 4; n++) {
        int c = wbase + n * 16 + l15;
        int cls = c / 196;
        msv[n] = c - cls * 196;
        isLo[n] = (cls == clsLo);
        valid[n] = (c < NREAL);
        invv[n] = valid[n] ? (1.0f / fmaxf(sqrtf(nrms[b * NREAL + c]), 1e-8f)) : 0.f;
    }
    int mtop = (wm == 0) ? 8 : 5;
    for (int m = 0; m < mtop; m++) {
        #pragma unroll
        for (int r = 0; r < 4; r++) {
            unsigned long long keyLo = 0ULL, keyHi = 0ULL;
            #pragma unroll
            for (int n = 0; n < 4; n++) {
                float v = acc[m][n][r] * invv[n];
                unsigned int ub = __float_as_uint(v);
                unsigned int su = (ub & 0x80000000u) ? ~ub : (ub | 0x80000000u);
                unsigned long long key = valid[n]
                    ? (((unsigned long long)su << 32) |
                       (unsigned long long)(0xFFFFFFFFu - (unsigned int)msv[n]))
                    : 0ULL;
                if (isLo[n]) keyLo = (key > keyLo) ? key : keyLo;
                else         keyHi = (key > keyHi) ? key : keyHi;
            }
            #pragma unroll
            for (int sft = 1; sft < 16; sft <<= 1) {
                unsigned long long o = __shfl_xor(keyLo, sft, 64);
                if (o > keyLo) keyLo = o;
            }
            if (hasHi) {
                #pragma unroll
                for (int sft = 1; sft < 16; sft <<= 1) {
                    unsigned long long o = __shfl_xor(keyHi, sft, 64);
                    if (o > keyHi) keyHi = o;
                }
            }
            if (l15 == 0) {
                int gm = wm * 128 + m * 16 + q * 4 + r;
                if (gm < MM) {
                    if (keyLo)
                        atomicMax(&gstat[((size_t)bq * NWAY + clsLo) * MP + gm], keyLo);
                    if (hasHi && keyHi)
                        atomicMax(&gstat[((size_t)bq * NWAY + clsHi) * MP + gm], keyHi);
                }
            }
        }
    }
}

// ---------------- mutual-NN mask + predict + per-sample CE -> atomicAdd out ----------------
__global__ void k_post(const unsigned long long* __restrict__ gstat,
                       const float* __restrict__ nrmq,
                       float* __restrict__ out, const int* __restrict__ qy) {
    int bq = blockIdx.x;
    int t = threadIdx.x;
    __shared__ float invq_s[MM];
    __shared__ float cm[NWAY * MM];
    __shared__ int   ca[NWAY * MM];
    __shared__ float gmax[MM];
    __shared__ int   jst[MM];
    __shared__ int   msk[MM];
    __shared__ float pred[NWAY];

    if (t < MM) invq_s[t] = 1.0f / fmaxf(sqrtf(nrmq[bq * MM + t]), 1e-8f);
    __syncthreads();

    for (int i = t; i < NWAY * MM; i += 256) {
        int n = i / MM, m = i - n * MM;
        unsigned long long key = gstat[((size_t)bq * NWAY + n) * MP + m];
        unsigned int hi = (unsigned int)(key >> 32);
        unsigned int bits = (hi & 0x80000000u) ? (hi ^ 0x80000000u) : ~hi;
        cm[i] = __uint_as_float(bits) * invq_s[m];
        ca[i] = (int)(0xFFFFFFFFu - (unsigned int)(key & 0xFFFFFFFFu));
    }
    __syncthreads();

    if (t < MM) {       // cross-class combine: ascending n, strict > == n-major first-index
        float bv = cm[t];
        int bj = ca[t];
        for (int n = 1; n < NWAY; n++) {
            float v = cm[n * MM + t];
            if (v > bv) { bv = v; bj = n * MM + ca[n * MM + t]; }
        }
        gmax[t] = bv; jst[t] = bj;
    }
    __syncthreads();

    if (t < MM) {       // mutual-NN: winner of my support-column group (max gmax, min index)
        int myj = jst[t];
        float myv = gmax[t];
        int lose = 0;
        for (int m2 = 0; m2 < MM; m2++) {
            if (jst[m2] == myj &&
                (gmax[m2] > myv || (gmax[m2] == myv && m2 < t))) lose = 1;
        }
        msk[t] = !lose;
    }
    __syncthreads();

    if (t < NWAY) {
        float p = 0.f;
        for (int m = 0; m < MM; m++) if (msk[m]) p += cm[t * MM + m];
        pred[t] = 2.0f * p;   // TEMPERATURE = 2
    }
    __syncthreads();

    if (t == 0) {
        float pm = pred[0];
        for (int n = 1; n < NWAY; n++) pm = fmaxf(pm, pred[n]);
        float s = 0.f;
        for (int n = 0; n < NWAY; n++) s += expf(pred[n] - pm);
        float lse = pm + logf(s);
        int y = qy[bq];
        atomicAdd(out, (lse - pred[y]) * (1.0f / (BB * QQ)));
    }
}

extern "C" void kernel_launch(void* const* d_in, const int* in_sizes, int n_in,
                              void* d_out, int out_size, void* d_ws, size_t ws_size,
                              hipStream_t stream) {
    const float* sx = (const float*)d_in[0];
    const float* qx = (const float*)d_in[2];
    const int*   qy = (const int*)d_in[3];
    float* out = (float*)d_out;
    float* ws  = (float*)d_ws;

    _Float16* Bpk = (_Float16*)(ws + BPK_OFF);
    _Float16* Apk = (_Float16*)(ws + APK_OFF);
    unsigned long long* gstat = (unsigned long long*)(ws + GSTAT_OFF);
    float* nrms = ws + NRMS_OFF;
    float* nrmq = ws + NRMQ_OFF;

    // zero gstat + nrms + nrmq (contiguous) and the output accumulator
    hipMemsetAsync(gstat, 0, (size_t)(2 * GSTAT_N + NRMS_SZ + NRMQ_SZ) * 4, stream);
    hipMemsetAsync(out, 0, 4, stream);
    hipLaunchKernelGGL(k_prep, dim3(3200), dim3(256), 0, stream, sx, qx, Apk, Bpk, nrmq, nrms);
    hipLaunchKernelGGL(k_sim,  dim3(1200), dim3(512), 0, stream, Apk, Bpk, nrms, gstat);
    hipLaunchKernelGGL(k_post, dim3(300), dim3(256), 0, stream, gstat, nrmq, out, qy);
}

// Round 2
// 465.575 us; speedup vs baseline: 2.2980x; 2.2980x over previous
//
#include <hip/hip_runtime.h>
#include <math.h>

#define NWAY 5
#define KSHOT 5
#define BB 4
#define QQ 75
#define CC 640
#define MM 196
#define BQ (BB*QQ)          // 300
#define MP 208              // packed A rows per bq
#define NCOL 1024           // padded flat col space (980 real)
#define NREAL 980

// ---- ws layout (float offsets) ----
#define BPK_OFF   0
#define BPK_SZF   (BB*NCOL*CC/2)            // 1,310,720 (fp16 region)
#define APK_OFF   (BPK_OFF + BPK_SZF)
#define APK_SZF   ((BQ*MP + 64)*CC/2)       // +64 pad rows so 256-row tile OOB stays in-region
#define GSTAT_OFF (APK_OFF + APK_SZF)       // even -> 8B aligned
#define GSTAT_N   (BQ*NWAY*MP)              // 312,000 u64
#define NRMS_OFF  (GSTAT_OFF + 2*GSTAT_N)
#define NRMS_SZ   (BB*NWAY*MM)              // 3,920
#define NRMQ_OFF  (NRMS_OFF + NRMS_SZ)
#define NRMQ_SZ   (BQ*MM)                   // 58,800

typedef __attribute__((ext_vector_type(8))) _Float16 half8;
typedef __attribute__((ext_vector_type(4))) float floatx4;

// ---------------- fused prep: A-pack (3000 blocks) + B mean-pack (200 blocks) ----------------
__global__ void k_prep(const float* __restrict__ sx, const float* __restrict__ qx,
                       _Float16* __restrict__ Apk, _Float16* __restrict__ Bpk,
                       float* __restrict__ nrmq, float* __restrict__ nrms) {
    __shared__ float T[64 * 197];         // 50,432 B
    int t = threadIdx.x;
    int blk = blockIdx.x;
    if (blk < 3000) {
        // ---- query pack: Apk[bq][m][c] fp16 (unnormalized) + nrmq partials ----
        int bq = blk / 10, cc = blk % 10;
        int c0 = cc * 64;
        const float* Q = qx + (size_t)bq * CC * MM + (size_t)c0 * MM;
        for (int idx = t; idx < 64 * MM; idx += 256) {
            int ci = idx / MM, m = idx - ci * MM;
            T[ci * 197 + m] = Q[idx];
        }
        __syncthreads();
        _Float16* out = Apk + (size_t)bq * MP * CC;
        int mloc = t >> 3, cj8 = t & 7;   // 32 rows x 8 col-groups per pass
        #pragma unroll
        for (int r = 0; r < 7; r++) {
            int mm = r * 32 + mloc;
            if (mm < MP) {
                half8 v;
                #pragma unroll
                for (int k = 0; k < 8; k++) {
                    float f = (mm < MM) ? T[(cj8 * 8 + k) * 197 + mm] : 0.f;
                    v[k] = (_Float16)f;
                }
                *(half8*)&out[(size_t)mm * CC + c0 + cj8 * 8] = v;
            }
        }
        if (t < MM) {
            float ss = 0.f;
            for (int ci = 0; ci < 64; ci++) { float v = T[ci * 197 + t]; ss += v * v; }
            atomicAdd(&nrmq[bq * MM + t], ss);
        }
    } else {
        // ---- support k-shot mean + pack: Bpk[b][col=n*196+ms][c] fp16 (unnormalized) + nrms ----
        int bb = blk - 3000;
        int bn = bb / 10, cc = bb % 10;
        int b = bn / NWAY, n = bn % NWAY;
        int c0 = cc * 64;
        const float* S = sx + (size_t)bn * KSHOT * CC * MM + (size_t)c0 * MM;
        for (int idx = t; idx < 64 * MM; idx += 256) {
            int ci = idx / MM, m = idx - ci * MM;
            float s = 0.f;
            #pragma unroll
            for (int k = 0; k < KSHOT; k++) s += S[(size_t)k * CC * MM + idx];
            T[ci * 197 + m] = s * 0.2f;
        }
        __syncthreads();
        _Float16* out = Bpk + ((size_t)b * NCOL + (size_t)n * MM) * CC;
        int mloc = t >> 3, cj8 = t & 7;
        #pragma unroll
        for (int r = 0; r < 7; r++) {
            int mm = r * 32 + mloc;
            if (mm < MM) {
                half8 v;
                #pragma unroll
                for (int k = 0; k < 8; k++)
                    v[k] = (_Float16)T[(cj8 * 8 + k) * 197 + mm];
                *(half8*)&out[(size_t)mm * CC + c0 + cj8 * 8] = v;
            }
        }
        if (t < MM) {
            float ss = 0.f;
            for (int ci = 0; ci < 64; ci++) { float v = T[ci * 197 + t]; ss += v * v; }
            atomicAdd(&nrms[bn * MM + t], ss);
        }
    }
}

// ---------------- MFMA similarity v2b: 256x256 tile, 8 waves (2Mx4N), BK=64 ----------------
// LDS 128 KiB: 2 buffers x { A 256x64 halfs | B 256x64 halfs }, chunk-XOR swizzled rows.
// Pipeline: stage tile t+1 -> buf (t+1)&1 BEFORE computing tile t from buf t&1; one
// __syncthreads per K-tile (its vmcnt(0) drain lands a full compute-phase after issue).
// wm=1 waves skip mrep 5..7 (rows 208..255 are pad garbage): -18.75% MFMA.
// NOTE (rule #20): every acc[][] access must be statically indexed — the epilogue m-loop
// is fully unrolled with a uniform `continue` guard, NOT a runtime trip count. A runtime
// bound here demotes acc to scratch (2.9 GB spill traffic measured in round 1).
__global__ __launch_bounds__(512, 2) void k_sim(
    const _Float16* __restrict__ Apk, const _Float16* __restrict__ Bpk,
    const float* __restrict__ nrms, unsigned long long* __restrict__ gstat)
{
    __shared__ __align__(16) _Float16 Lds[65536];   // 131,072 B

    int hw = blockIdx.x;
    int logical = (hw & 7) * 150 + (hw >> 3);   // XCD-bijective: 4 col-blocks of a bq per XCD
    int bq = logical >> 2, cblk = logical & 3;
    int b = bq / QQ;

    int t = threadIdx.x, w = t >> 6, lane = t & 63;
    int wm = w >> 2, wn = w & 3;
    int q = lane >> 4, l15 = lane & 15, s7 = l15 & 7;

    const _Float16* Ab = Apk + (size_t)bq * MP * CC;
    const _Float16* Bb = Bpk + ((size_t)b * NCOL + (size_t)cblk * 256) * CC;

    // staging source offsets (halfs): call a covers rows/cols a*64 .. +63, 8KB per call
    int voff[4];
    {
        int rr = t >> 3, slot = t & 7;
        #pragma unroll
        for (int a = 0; a < 4; a++) {
            int r = a * 64 + rr;
            voff[a] = r * CC + ((slot ^ (r & 7)) << 3);
        }
    }

    // fragment read bases (halfs, within one 32768-half buffer)
    int aoff[8], boff[4];
    #pragma unroll
    for (int m = 0; m < 8; m++) aoff[m] = (wm * 128 + m * 16 + l15) * 64;
    #pragma unroll
    for (int n = 0; n < 4; n++) boff[n] = 16384 + (wn * 64 + n * 16 + l15) * 64;

    floatx4 acc[8][4];
    #pragma unroll
    for (int m = 0; m < 8; m++)
        #pragma unroll
        for (int n = 0; n < 4; n++) acc[m][n] = (floatx4){0.f, 0.f, 0.f, 0.f};

    #define STAGE(TT)                                                                  \
        do {                                                                           \
            int nb_ = ((TT) & 1) << 15;                                                \
            int c0_ = (TT) * 64;                                                       \
            _Pragma("unroll")                                                          \
            for (int a = 0; a < 4; a++) {                                              \
                __builtin_amdgcn_global_load_lds(                                      \
                    (const __attribute__((address_space(1))) void*)(Ab + voff[a] + c0_),\
                    (__attribute__((address_space(3))) void*)(Lds + nb_ + a * 4096 + w * 512), \
                    16, 0, 0);                                                         \
                __builtin_amdgcn_global_load_lds(                                      \
                    (const __attribute__((address_space(1))) void*)(Bb + voff[a] + c0_),\
                    (__attribute__((address_space(3))) void*)(Lds + nb_ + 16384 + a * 4096 + w * 512), \
                    16, 0, 0);                                                         \
            }                                                                          \
        } while (0)

    // prologue: tile 0 -> buf 0
    STAGE(0);
    __syncthreads();

    for (int tt = 0; tt < 10; tt++) {
        int cb = (tt & 1) << 15;
        if (tt < 9) STAGE(tt + 1);          // issue next tile into the other buffer

        half8 bf[4][2];
        #pragma unroll
        for (int n = 0; n < 4; n++)
            #pragma unroll
            for (int ks = 0; ks < 2; ks++)
                bf[n][ks] = *(const half8*)&Lds[cb + boff[n] + (((ks * 4 + q) ^ s7) << 3)];

        __builtin_amdgcn_s_setprio(1);
        #define MFMA_BLOCK(MTOP)                                                       \
            _Pragma("unroll")                                                          \
            for (int m = 0; m < (MTOP); m++) {                                         \
                half8 af0 = *(const half8*)&Lds[cb + aoff[m] + ((q ^ s7) << 3)];       \
                half8 af1 = *(const half8*)&Lds[cb + aoff[m] + (((4 + q) ^ s7) << 3)]; \
                _Pragma("unroll")                                                      \
                for (int n = 0; n < 4; n++) {                                          \
                    acc[m][n] = __builtin_amdgcn_mfma_f32_16x16x32_f16(af0, bf[n][0], acc[m][n], 0, 0, 0); \
                    acc[m][n] = __builtin_amdgcn_mfma_f32_16x16x32_f16(af1, bf[n][1], acc[m][n], 0, 0, 0); \
                }                                                                      \
            }
        if (wm == 0) { MFMA_BLOCK(8) } else { MFMA_BLOCK(5) }   // wm=1 rows >=208 are pad
        __builtin_amdgcn_s_setprio(0);

        __syncthreads();   // vmcnt(0)+lgkmcnt(0)+barrier: drains the t+1 loads issued above
    }

    // ---- epilogue: fold 4 nrep cols into <=2 class keys, 16-lane butterfly, atomicMax ----
    int wbase = cblk * 256 + wn * 64;     // 64-col window, straddles <=1 class boundary
    int clsLo = wbase / 196;
    int clsHi = clsLo + 1;
    bool hasHi = (((wbase + 63) / 196) != clsLo) && (clsHi < NWAY);
    float invv[4]; int msv[4], isLo[4], valid[4];
    #pragma unroll
    for (int n = 0; n < 4; n++) {
        int c = wbase + n * 16 + l15;
        int cls = c / 196;
        msv[n] = c - cls * 196;
        isLo[n] = (cls == clsLo);
        valid[n] = (c < NREAL);
        invv[n] = valid[n] ? (1.0f / fmaxf(sqrtf(nrms[b * NREAL + c]), 1e-8f)) : 0.f;
    }
    #pragma unroll
    for (int m = 0; m < 8; m++) {                 // static bound: acc stays in VGPRs
        if (wm == 1 && m >= 5) continue;          // uniform guard; rows >=208 are pad
        #pragma unroll
        for (int r = 0; r < 4; r++) {
            unsigned long long keyLo = 0ULL, keyHi = 0ULL;
            #pragma unroll
            for (int n = 0; n < 4; n++) {
                float v = acc[m][n][r] * invv[n];
                unsigned int ub = __float_as_uint(v);
                unsigned int su = (ub & 0x80000000u) ? ~ub : (ub | 0x80000000u);
                unsigned long long key = valid[n]
                    ? (((unsigned long long)su << 32) |
                       (unsigned long long)(0xFFFFFFFFu - (unsigned int)msv[n]))
                    : 0ULL;
                if (isLo[n]) keyLo = (key > keyLo) ? key : keyLo;
                else         keyHi = (key > keyHi) ? key : keyHi;
            }
            #pragma unroll
            for (int sft = 1; sft < 16; sft <<= 1) {
                unsigned long long o = __shfl_xor(keyLo, sft, 64);
                if (o > keyLo) keyLo = o;
            }
            if (hasHi) {
                #pragma unroll
                for (int sft = 1; sft < 16; sft <<= 1) {
                    unsigned long long o = __shfl_xor(keyHi, sft, 64);
                    if (o > keyHi) keyHi = o;
                }
            }
            if (l15 == 0) {
                int gm = wm * 128 + m * 16 + q * 4 + r;
                if (gm < MM) {
                    if (keyLo)
                        atomicMax(&gstat[((size_t)bq * NWAY + clsLo) * MP + gm], keyLo);
                    if (hasHi && keyHi)
                        atomicMax(&gstat[((size_t)bq * NWAY + clsHi) * MP + gm], keyHi);
                }
            }
        }
    }
}

// ---------------- mutual-NN mask + predict + per-sample CE -> atomicAdd out ----------------
__global__ void k_post(const unsigned long long* __restrict__ gstat,
                       const float* __restrict__ nrmq,
                       float* __restrict__ out, const int* __restrict__ qy) {
    int bq = blockIdx.x;
    int t = threadIdx.x;
    __shared__ float invq_s[MM];
    __shared__ float cm[NWAY * MM];
    __shared__ int   ca[NWAY * MM];
    __shared__ float gmax[MM];
    __shared__ int   jst[MM];
    __shared__ int   msk[MM];
    __shared__ float pred[NWAY];

    if (t < MM) invq_s[t] = 1.0f / fmaxf(sqrtf(nrmq[bq * MM + t]), 1e-8f);
    __syncthreads();

    for (int i = t; i < NWAY * MM; i += 256) {
        int n = i / MM, m = i - n * MM;
        unsigned long long key = gstat[((size_t)bq * NWAY + n) * MP + m];
        unsigned int hi = (unsigned int)(key >> 32);
        unsigned int bits = (hi & 0x80000000u) ? (hi ^ 0x80000000u) : ~hi;
        cm[i] = __uint_as_float(bits) * invq_s[m];
        ca[i] = (int)(0xFFFFFFFFu - (unsigned int)(key & 0xFFFFFFFFu));
    }
    __syncthreads();

    if (t < MM) {       // cross-class combine: ascending n, strict > == n-major first-index
        float bv = cm[t];
        int bj = ca[t];
        for (int n = 1; n < NWAY; n++) {
            float v = cm[n * MM + t];
            if (v > bv) { bv = v; bj = n * MM + ca[n * MM + t]; }
        }
        gmax[t] = bv; jst[t] = bj;
    }
    __syncthreads();

    if (t < MM) {       // mutual-NN: winner of my support-column group (max gmax, min index)
        int myj = jst[t];
        float myv = gmax[t];
        int lose = 0;
        for (int m2 = 0; m2 < MM; m2++) {
            if (jst[m2] == myj &&
                (gmax[m2] > myv || (gmax[m2] == myv && m2 < t))) lose = 1;
        }
        msk[t] = !lose;
    }
    __syncthreads();

    if (t < NWAY) {
        float p = 0.f;
        for (int m = 0; m < MM; m++) if (msk[m]) p += cm[t * MM + m];
        pred[t] = 2.0f * p;   // TEMPERATURE = 2
    }
    __syncthreads();

    if (t == 0) {
        float pm = pred[0];
        for (int n = 1; n < NWAY; n++) pm = fmaxf(pm, pred[n]);
        float s = 0.f;
        for (int n = 0; n < NWAY; n++) s += expf(pred[n] - pm);
        float lse = pm + logf(s);
        int y = qy[bq];
        atomicAdd(out, (lse - pred[y]) * (1.0f / (BB * QQ)));
    }
}

extern "C" void kernel_launch(void* const* d_in, const int* in_sizes, int n_in,
                              void* d_out, int out_size, void* d_ws, size_t ws_size,
                              hipStream_t stream) {
    const float* sx = (const float*)d_in[0];
    const float* qx = (const float*)d_in[2];
    const int*   qy = (const int*)d_in[3];
    float* out = (float*)d_out;
    float* ws  = (float*)d_ws;

    _Float16* Bpk = (_Float16*)(ws + BPK_OFF);
    _Float16* Apk = (_Float16*)(ws + APK_OFF);
    unsigned long long* gstat = (unsigned long long*)(ws + GSTAT_OFF);
    float* nrms = ws + NRMS_OFF;
    float* nrmq = ws + NRMQ_OFF;

    // zero gstat + nrms + nrmq (contiguous) and the output accumulator
    hipMemsetAsync(gstat, 0, (size_t)(2 * GSTAT_N + NRMS_SZ + NRMQ_SZ) * 4, stream);
    hipMemsetAsync(out, 0, 4, stream);
    hipLaunchKernelGGL(k_prep, dim3(3200), dim3(256), 0, stream, sx, qx, Apk, Bpk, nrmq, nrms);
    hipLaunchKernelGGL(k_sim,  dim3(1200), dim3(512), 0, stream, Apk, Bpk, nrms, gstat);
    hipLaunchKernelGGL(k_post, dim3(300), dim3(256), 0, stream, gstat, nrmq, out, qy);
}